// Round 1
// 252.999 us; speedup vs baseline: 1.0048x; 1.0048x over previous
//
#include <hip/hip_runtime.h>
#include <stdint.h>
#include <math.h>

#define CLASSNUM 10575
#define NPAD     10752   // 84 * 128, B-tile padded; pad rows zeroed
#define BATCH    4096
#define KDIM     512
#define BM       256
#define BN       128
#define BK       64
#define NKT      (KDIM / BK)   // 8 K-tiles
#define MARGIN   0.2f
#define SCALE    32.0f
#define EPS2     1.0e-4f
#define FLAG_THR 0.58f   // guard band below the 0.6 branch point

typedef __bf16 bf16_t;
typedef __attribute__((ext_vector_type(8))) __bf16 bf16x8;
typedef __attribute__((ext_vector_type(4))) float f32x4;

__device__ __forceinline__ unsigned short f2bf(float f) {
  union { float f; unsigned u; } v; v.f = f;
  return (unsigned short)((v.u + 0x7FFFu + ((v.u >> 16) & 1u)) >> 16);  // RNE
}

__device__ __forceinline__ void async_ld16(const void* g, void* lds) {
  __builtin_amdgcn_global_load_lds(
      (__attribute__((address_space(1))) void*)(const_cast<void*>(g)),
      (__attribute__((address_space(3))) void*)lds, 16, 0, 0);
}

// ---------------- prep: row L2-normalize fp32 -> bf16 (one wave per row) ---
__global__ __launch_bounds__(256) void normalize_rows_bf16(
    const float* __restrict__ src, unsigned short* __restrict__ dst,
    int nrows, int nrows_pad) {
  int row  = blockIdx.x * 4 + (threadIdx.x >> 6);
  int lane = threadIdx.x & 63;
  if (row >= nrows_pad) return;
  unsigned short o[8] = {0,0,0,0,0,0,0,0};
  if (row < nrows) {
    const float4* rp = (const float4*)(src + (size_t)row * KDIM);
    float4 a = rp[lane * 2 + 0];
    float4 b = rp[lane * 2 + 1];
    float ss = a.x*a.x + a.y*a.y + a.z*a.z + a.w*a.w
             + b.x*b.x + b.y*b.y + b.z*b.z + b.w*b.w;
    #pragma unroll
    for (int off = 32; off > 0; off >>= 1) ss += __shfl_xor(ss, off, 64);
    float rn = 1.0f / fmaxf(sqrtf(ss), 1e-12f);
    o[0]=f2bf(a.x*rn); o[1]=f2bf(a.y*rn); o[2]=f2bf(a.z*rn); o[3]=f2bf(a.w*rn);
    o[4]=f2bf(b.x*rn); o[5]=f2bf(b.y*rn); o[6]=f2bf(b.z*rn); o[7]=f2bf(b.w*rn);
  }
  ushort4* dp = (ushort4*)(dst + (size_t)row * KDIM);
  dp[lane*2+0] = make_ushort4(o[0],o[1],o[2],o[3]);
  dp[lane*2+1] = make_ushort4(o[4],o[5],o[6],o[7]);
}

// ------- prep: exact fp32 label cosine + precomputed 32*score + flag=0 ----
__global__ __launch_bounds__(256) void label_cos_kernel(
    const float* __restrict__ x, const float* __restrict__ w,
    const int* __restrict__ label, float* __restrict__ cls,
    float* __restrict__ score32, unsigned* __restrict__ flags) {
  int row  = blockIdx.x * 4 + (threadIdx.x >> 6);
  int lane = threadIdx.x & 63;
  if (row >= BATCH) return;
  int l = label[row];
  const float4* xp = (const float4*)(x + (size_t)row * KDIM);
  const float4* wp = (const float4*)(w + (size_t)l * KDIM);
  float dxx = 0.f, dww = 0.f, dxw = 0.f;
  #pragma unroll
  for (int i = 0; i < 2; ++i) {
    float4 a = xp[lane*2+i];
    float4 b = wp[lane*2+i];
    dxx += a.x*a.x + a.y*a.y + a.z*a.z + a.w*a.w;
    dww += b.x*b.x + b.y*b.y + b.z*b.z + b.w*b.w;
    dxw += a.x*b.x + a.y*b.y + a.z*b.z + a.w*b.w;
  }
  #pragma unroll
  for (int off = 32; off > 0; off >>= 1) {
    dxx += __shfl_xor(dxx, off, 64);
    dww += __shfl_xor(dww, off, 64);
    dxw += __shfl_xor(dxw, off, 64);
  }
  if (lane == 0) {
    float c = dxw / (fmaxf(sqrtf(dxx), 1e-12f) * fmaxf(sqrtf(dww), 1e-12f));
    c = fminf(fmaxf(c, -1.0f), 1.0f);
    cls[row] = c;
    score32[row] = SCALE * ((c > 0.0f) ? (c - MARGIN) : c);
    flags[row] = 0u;
  }
}

// ---- GEMM 256x128 tile, 512 thr / 8 waves (4M x 2N), BK=64 ---------------
// 3-deep LDS ring (144 KB), 2-tiles-ahead prefetch, counted vmcnt(6) per
// tile entry (T3+T4), raw s_barrier (no __syncthreads drain in loop),
// setprio around each 16-MFMA cluster (T5).
// Race-safety: staging tile t+2 targets slot (t+2)%3 == (t-1)%3, whose last
// reads complete before tile t's entry barrier; writes to that slot are
// only read at tile t+2, guarded by its entry vmcnt+barrier.
// LDS chunk for (row,q) stored at p = q ^ (row&7): frag reads 2-way bank
// alias = free (m136). Epilogue fuses 32*clip, per-row flag, label scatter.

#define ABUF_B 32768                    // 256 * 64 * 2B
#define BBUF_B 16384                    // 128 * 64 * 2B
#define BUF_B  (ABUF_B + BBUF_B)        // 48 KB per ring slot

struct Frags { bf16x8 a[4]; bf16x8 b[4]; };

__device__ __forceinline__ Frags ld_frags(const char* base, int ksub,
                                          int waveM, int waveN,
                                          int fr, int fq) {
  Frags f;
  const bf16_t* Ab = (const bf16_t*)base;
  const bf16_t* Bb = (const bf16_t*)(base + ABUF_B);
  const int q = ksub * 4 + fq;
  const int p = (q ^ (fr & 7)) * 8;     // row&7 == fr&7 for all frag rows
  #pragma unroll
  for (int i = 0; i < 4; ++i) {
    int ra = waveM * 64 + i * 16 + fr;
    f.a[i] = *(const bf16x8*)(Ab + ra * BK + p);
    int rb = waveN * 64 + i * 16 + fr;
    f.b[i] = *(const bf16x8*)(Bb + rb * BK + p);
  }
  return f;
}

__device__ __forceinline__ void mfma16(const Frags& f, f32x4 (&acc)[4][4]) {
  __builtin_amdgcn_s_setprio(1);
  #pragma unroll
  for (int mi = 0; mi < 4; ++mi)
    #pragma unroll
    for (int ni = 0; ni < 4; ++ni)
      acc[mi][ni] = __builtin_amdgcn_mfma_f32_16x16x32_bf16(
          f.a[mi], f.b[ni], acc[mi][ni], 0, 0, 0);
  __builtin_amdgcn_s_setprio(0);
}

__global__ __launch_bounds__(512) void gemm_bf16(
    const bf16_t* __restrict__ A,   // xn [BATCH][KDIM]
    const bf16_t* __restrict__ Bm,  // wn [NPAD][KDIM]
    float* __restrict__ out, unsigned* __restrict__ flags,
    const int* __restrict__ label, const float* __restrict__ score32) {
  __shared__ __align__(16) char lds[3 * BUF_B];   // 144 KB

  const int bm = blockIdx.x, bn = blockIdx.y;
  const int tid = threadIdx.x, lane = tid & 63, wave = tid >> 6;
  const int waveM = wave >> 1, waveN = wave & 1;   // 4 x 2 wave grid

  const f32x4 z4 = {0.f, 0.f, 0.f, 0.f};
  f32x4 acc[4][4];
  #pragma unroll
  for (int i = 0; i < 4; ++i)
    #pragma unroll
    for (int j = 0; j < 4; ++j) acc[i][j] = z4;

  // staging: thread tid -> row = R*64 + (tid>>3), LDS chunk pos = tid&7,
  // global chunk = (tid&7) ^ (row&7)  (row&7 == (tid>>3)&7, R-invariant).
  const int srow = tid >> 3;
  const int scg  = (tid & 7) ^ (srow & 7);
  const bf16_t* agB = A  + (size_t)(bm * BM + srow) * KDIM + scg * 8;
  const bf16_t* bgB = Bm + (size_t)(bn * BN + srow) * KDIM + scg * 8;

  const int fr = lane & 15;   // frag row within 16
  const int fq = lane >> 4;   // quad

  // stage half of tile t (part 0: A rows 0..127 + B rows 0..63;
  //                       part 1: A rows 128..255 + B rows 64..127)
  auto stage = [&](int t, int part) {
    char* base = lds + (t % 3) * BUF_B;
    const int kb = t * BK;
    const int Ra = part * 2;
    async_ld16(agB + (size_t)(Ra * 64) * KDIM + kb,
               base + Ra * 8192 + wave * 1024);
    async_ld16(agB + (size_t)((Ra + 1) * 64) * KDIM + kb,
               base + (Ra + 1) * 8192 + wave * 1024);
    async_ld16(bgB + (size_t)(part * 64) * KDIM + kb,
               base + ABUF_B + part * 8192 + wave * 1024);
  };

  // prologue: tiles 0 and 1 in flight (12 loads/thread)
  stage(0, 0); stage(0, 1);
  stage(1, 0); stage(1, 1);

  #pragma unroll 1
  for (int t = 0; t < NKT - 1; ++t) {
    // tile t ready: own 6 newest (tile t+1) may stay in flight
    asm volatile("s_waitcnt vmcnt(6)" ::: "memory");
    asm volatile("s_barrier" ::: "memory");
    const char* base = lds + (t % 3) * BUF_B;

    Frags f0 = ld_frags(base, 0, waveM, waveN, fr, fq);
    if (t < NKT - 2) stage(t + 2, 0);
    asm volatile("s_barrier" ::: "memory");
    mfma16(f0, acc);

    Frags f1 = ld_frags(base, 1, waveM, waveN, fr, fq);
    if (t < NKT - 2) stage(t + 2, 1);
    asm volatile("s_barrier" ::: "memory");
    mfma16(f1, acc);
  }
  // peeled last tile: drain to 0 (only place vmcnt(0) appears)
  {
    asm volatile("s_waitcnt vmcnt(0)" ::: "memory");
    asm volatile("s_barrier" ::: "memory");
    const char* base = lds + ((NKT - 1) % 3) * BUF_B;
    Frags f0 = ld_frags(base, 0, waveM, waveN, fr, fq);
    mfma16(f0, acc);
    Frags f1 = ld_frags(base, 1, waveM, waveN, fr, fq);
    mfma16(f1, acc);
  }

  // stage this block's 256 labels + label scores into reused LDS
  __syncthreads();
  int*   labL   = (int*)lds;
  float* scoreL = (float*)(lds + 1024);
  if (tid < 256) {
    labL[tid]   = label[bm * BM + tid];
    scoreL[tid] = score32[bm * BM + tid];
  }
  __syncthreads();

  // epilogue: C/D layout col=lane&15, row=(lane>>4)*4+reg [m89-verified]
  const int colBase = bn * BN + waveN * 64 + fr;
  #pragma unroll
  for (int mi = 0; mi < 4; ++mi) {
    #pragma unroll
    for (int r = 0; r < 4; ++r) {
      int rloc = waveM * 64 + mi * 16 + fq * 4 + r;
      int row  = bm * BM + rloc;
      int lab  = labL[rloc];
      float sc = scoreL[rloc];
      float mx = -2.0f;
      #pragma unroll
      for (int ni = 0; ni < 4; ++ni) {
        int col = colBase + ni * 16;
        float v = fminf(fmaxf(acc[mi][ni][r], -1.0f), 1.0f);
        mx = fmaxf(mx, v);                       // flag uses cos incl. label
        float vs = (col == lab) ? sc : SCALE * v;
        if (col < CLASSNUM) out[(size_t)row * CLASSNUM + col] = vs;
      }
      if (mx > FLAG_THR) atomicOr(flags + row, 1u);
    }
  }
}

// ---------------- fixup: early-out unless flagged (rare/never) ------------
// Cold path: exact reference semantics; original label cos reconstructed
// from cls[] since the epilogue already scattered the label score.
__global__ __launch_bounds__(256) void fixup_kernel(
    float* __restrict__ out, const int* __restrict__ label,
    const float* __restrict__ cls, const unsigned* __restrict__ flags) {
  const int row  = blockIdx.x * 4 + (threadIdx.x >> 6);
  const int lane = threadIdx.x & 63;
  if (flags[row] == 0u) return;   // rival scatter value-invisible; label done

  float* orow = out + (size_t)row * CLASSNUM;
  const int lab = label[row];
  const float labv = SCALE * cls[row];   // original 32*cos at label position

  // pass 1: argmax (first-occurrence ties)
  float bv = -1e30f; int bi = 0;
  for (int i = lane; i < CLASSNUM; i += 64) {
    float v = (i == lab) ? labv : orow[i];
    if (v > bv) { bv = v; bi = i; }
  }
  #pragma unroll
  for (int off = 32; off > 0; off >>= 1) {
    float ov = __shfl_xor(bv, off, 64);
    int   oi = __shfl_xor(bi, off, 64);
    if (ov > bv || (ov == bv && oi < bi)) { bv = ov; bi = oi; }
  }
  const float cmax = bv * (1.0f / 32.0f);
  const int maxIdx = bi;

  // pass 2: Z
  float zz = 0.f;
  for (int i = lane; i < CLASSNUM; i += 64) {
    float v = (i == lab) ? labv : orow[i];
    zz += expf(v * (1.0f / 32.0f) - cmax);
  }
  #pragma unroll
  for (int off = 32; off > 0; off >>= 1) zz += __shfl_xor(zz, off, 64);
  const float Z = zz;
  const float thr = 1.0f / Z - EPS2;

  // pass 3: masked argmax (all-masked -> 0)
  float mbv = -1.0f; int mbi = 0;
  for (int i = lane; i < CLASSNUM; i += 64) {
    float v = (i == lab) ? labv : orow[i];
    float soft = expf(v * (1.0f / 32.0f) - cmax) / Z;
    float m = (soft < thr) ? soft : 0.0f;
    if (m > mbv) { mbv = m; mbi = i; }
  }
  #pragma unroll
  for (int off = 32; off > 0; off >>= 1) {
    float ov = __shfl_xor(mbv, off, 64);
    int   oi = __shfl_xor(mbi, off, 64);
    if (ov > mbv || (ov == mbv && oi < mbi)) { mbv = ov; mbi = oi; }
  }

  if (lane == 0) {
    int rival = (maxIdx == lab) ? mbi : maxIdx;
    float rc  = ((rival == lab) ? labv : orow[rival]) * (1.0f / 32.0f);
    float rs  = (rc > 0.6f) ? (rc + MARGIN) * 0.2f : rc;
    orow[rival] = SCALE * rs;                 // rival first
    float cl = cls[row];
    float scv = (cl > 0.0f) ? (cl - MARGIN) : cl;
    orow[lab] = SCALE * scv;                  // label wins collisions
  }
}

extern "C" void kernel_launch(void* const* d_in, const int* in_sizes, int n_in,
                              void* d_out, int out_size, void* d_ws, size_t ws_size,
                              hipStream_t stream) {
  const float* x     = (const float*)d_in[0];
  const int*   label = (const int*)d_in[1];
  const float* w     = (const float*)d_in[2];
  float* out = (float*)d_out;

  // ws: xn bf16 | wn bf16 (padded) | cls f32 | score32 f32 | flags u32
  unsigned short* xn = (unsigned short*)d_ws;
  unsigned short* wn = xn + (size_t)BATCH * KDIM;
  float* cls     = (float*)(wn + (size_t)NPAD * KDIM);
  float* score32 = cls + BATCH;
  unsigned* flags = (unsigned*)(score32 + BATCH);

  normalize_rows_bf16<<<BATCH / 4, 256, 0, stream>>>(x, xn, BATCH, BATCH);
  normalize_rows_bf16<<<NPAD / 4, 256, 0, stream>>>(w, wn, CLASSNUM, NPAD);
  label_cos_kernel<<<BATCH / 4, 256, 0, stream>>>(x, w, label, cls,
                                                  score32, flags);

  dim3 g(BATCH / BM, NPAD / BN);   // 16 x 84
  gemm_bf16<<<g, 512, 0, stream>>>((const bf16_t*)xn, (const bf16_t*)wn,
                                   out, flags, label, score32);

  fixup_kernel<<<BATCH / 4, 256, 0, stream>>>(out, label, cls, flags);
}

// Round 2
// 249.893 us; speedup vs baseline: 1.0173x; 1.0124x over previous
//
#include <hip/hip_runtime.h>
#include <stdint.h>
#include <math.h>

#define CLASSNUM 10575
#define NPAD     10752   // 84 * 128, B-tile padded; pad rows zeroed
#define BATCH    4096
#define KDIM     512
#define BM       256
#define BN       128
#define BK       64
#define NKT      (KDIM / BK)   // 8 K-tiles
#define MARGIN   0.2f
#define SCALE    32.0f
#define EPS2     1.0e-4f
#define FLAG_THR 0.58f   // guard band below the 0.6 branch point

typedef __bf16 bf16_t;
typedef __attribute__((ext_vector_type(8))) __bf16 bf16x8;
typedef __attribute__((ext_vector_type(4))) float f32x4;

__device__ __forceinline__ unsigned short f2bf(float f) {
  union { float f; unsigned u; } v; v.f = f;
  return (unsigned short)((v.u + 0x7FFFu + ((v.u >> 16) & 1u)) >> 16);  // RNE
}

__device__ __forceinline__ void async_ld16(const void* g, void* lds) {
  __builtin_amdgcn_global_load_lds(
      (__attribute__((address_space(1))) void*)(const_cast<void*>(g)),
      (__attribute__((address_space(3))) void*)lds, 16, 0, 0);
}

// ---------------- prep (fused, one launch, 3 independent phases) ----------
// blocks [0, 1024)           : L2-normalize x rows fp32 -> bf16
// blocks [1024, 1024+2688)   : L2-normalize w rows fp32 -> bf16 (pad zeroed)
// blocks [3712, 3712+1024)   : exact fp32 label cosine + 32*score + flag=0
// Branch is block-uniform -> no divergence. One wave per row everywhere.

__device__ __forceinline__ void norm_row_body(
    const float* __restrict__ src, unsigned short* __restrict__ dst,
    int row, int lane, int nrows) {
  unsigned short o[8] = {0,0,0,0,0,0,0,0};
  if (row < nrows) {
    const float4* rp = (const float4*)(src + (size_t)row * KDIM);
    float4 a = rp[lane * 2 + 0];
    float4 b = rp[lane * 2 + 1];
    float ss = a.x*a.x + a.y*a.y + a.z*a.z + a.w*a.w
             + b.x*b.x + b.y*b.y + b.z*b.z + b.w*b.w;
    #pragma unroll
    for (int off = 32; off > 0; off >>= 1) ss += __shfl_xor(ss, off, 64);
    float rn = 1.0f / fmaxf(sqrtf(ss), 1e-12f);
    o[0]=f2bf(a.x*rn); o[1]=f2bf(a.y*rn); o[2]=f2bf(a.z*rn); o[3]=f2bf(a.w*rn);
    o[4]=f2bf(b.x*rn); o[5]=f2bf(b.y*rn); o[6]=f2bf(b.z*rn); o[7]=f2bf(b.w*rn);
  }
  ushort4* dp = (ushort4*)(dst + (size_t)row * KDIM);
  dp[lane*2+0] = make_ushort4(o[0],o[1],o[2],o[3]);
  dp[lane*2+1] = make_ushort4(o[4],o[5],o[6],o[7]);
}

__global__ __launch_bounds__(256) void prep_fused(
    const float* __restrict__ x, const float* __restrict__ w,
    const int* __restrict__ label,
    unsigned short* __restrict__ xn, unsigned short* __restrict__ wn,
    float* __restrict__ cls, float* __restrict__ score32,
    unsigned* __restrict__ flags) {
  const int b    = blockIdx.x;
  const int sub  = threadIdx.x >> 6;
  const int lane = threadIdx.x & 63;

  if (b < BATCH / 4) {                       // x rows
    norm_row_body(x, xn, b * 4 + sub, lane, BATCH);
    return;
  }
  if (b < BATCH / 4 + NPAD / 4) {            // w rows (pad rows zeroed)
    norm_row_body(w, wn, (b - BATCH / 4) * 4 + sub, lane, CLASSNUM);
    return;
  }
  // label cosine (exact fp32)
  const int row = (b - BATCH / 4 - NPAD / 4) * 4 + sub;
  if (row >= BATCH) return;
  int l = label[row];
  const float4* xp = (const float4*)(x + (size_t)row * KDIM);
  const float4* wp = (const float4*)(w + (size_t)l * KDIM);
  float dxx = 0.f, dww = 0.f, dxw = 0.f;
  #pragma unroll
  for (int i = 0; i < 2; ++i) {
    float4 a = xp[lane*2+i];
    float4 b4 = wp[lane*2+i];
    dxx += a.x*a.x + a.y*a.y + a.z*a.z + a.w*a.w;
    dww += b4.x*b4.x + b4.y*b4.y + b4.z*b4.z + b4.w*b4.w;
    dxw += a.x*b4.x + a.y*b4.y + a.z*b4.z + a.w*b4.w;
  }
  #pragma unroll
  for (int off = 32; off > 0; off >>= 1) {
    dxx += __shfl_xor(dxx, off, 64);
    dww += __shfl_xor(dww, off, 64);
    dxw += __shfl_xor(dxw, off, 64);
  }
  if (lane == 0) {
    float c = dxw / (fmaxf(sqrtf(dxx), 1e-12f) * fmaxf(sqrtf(dww), 1e-12f));
    c = fminf(fmaxf(c, -1.0f), 1.0f);
    cls[row] = c;
    score32[row] = SCALE * ((c > 0.0f) ? (c - MARGIN) : c);
    flags[row] = 0u;
  }
}

// ---- GEMM 256x128 tile, 512 thr / 8 waves (4M x 2N), BK=64 ---------------
// 3-deep LDS ring (144 KB), 2-tiles-ahead prefetch, counted vmcnt(6) per
// tile entry (T3+T4), raw s_barrier (no __syncthreads drain in loop),
// setprio around each 16-MFMA cluster (T5). Verified round 1.
// Race-safety: staging tile t+2 targets slot (t+2)%3 == (t-1)%3, whose last
// reads complete before tile t's entry barrier; writes to that slot are
// only read at tile t+2, guarded by its entry vmcnt+barrier.
// LDS chunk for (row,q) stored at p = q ^ (row&7): frag reads 2-way bank
// alias = free (m136). Epilogue fuses 32*clip, per-row flag, label scatter.

#define ABUF_B 32768                    // 256 * 64 * 2B
#define BBUF_B 16384                    // 128 * 64 * 2B
#define BUF_B  (ABUF_B + BBUF_B)        // 48 KB per ring slot

struct Frags { bf16x8 a[4]; bf16x8 b[4]; };

__device__ __forceinline__ Frags ld_frags(const char* base, int ksub,
                                          int waveM, int waveN,
                                          int fr, int fq) {
  Frags f;
  const bf16_t* Ab = (const bf16_t*)base;
  const bf16_t* Bb = (const bf16_t*)(base + ABUF_B);
  const int q = ksub * 4 + fq;
  const int p = (q ^ (fr & 7)) * 8;     // row&7 == fr&7 for all frag rows
  #pragma unroll
  for (int i = 0; i < 4; ++i) {
    int ra = waveM * 64 + i * 16 + fr;
    f.a[i] = *(const bf16x8*)(Ab + ra * BK + p);
    int rb = waveN * 64 + i * 16 + fr;
    f.b[i] = *(const bf16x8*)(Bb + rb * BK + p);
  }
  return f;
}

__device__ __forceinline__ void mfma16(const Frags& f, f32x4 (&acc)[4][4]) {
  __builtin_amdgcn_s_setprio(1);
  #pragma unroll
  for (int mi = 0; mi < 4; ++mi)
    #pragma unroll
    for (int ni = 0; ni < 4; ++ni)
      acc[mi][ni] = __builtin_amdgcn_mfma_f32_16x16x32_bf16(
          f.a[mi], f.b[ni], acc[mi][ni], 0, 0, 0);
  __builtin_amdgcn_s_setprio(0);
}

__global__ __launch_bounds__(512) void gemm_bf16(
    const bf16_t* __restrict__ A,   // xn [BATCH][KDIM]
    const bf16_t* __restrict__ Bm,  // wn [NPAD][KDIM]
    float* __restrict__ out, unsigned* __restrict__ flags,
    const int* __restrict__ label, const float* __restrict__ score32) {
  __shared__ __align__(16) char lds[3 * BUF_B];   // 144 KB

  const int bm = blockIdx.x, bn = blockIdx.y;
  const int tid = threadIdx.x, lane = tid & 63, wave = tid >> 6;
  const int waveM = wave >> 1, waveN = wave & 1;   // 4 x 2 wave grid

  const f32x4 z4 = {0.f, 0.f, 0.f, 0.f};
  f32x4 acc[4][4];
  #pragma unroll
  for (int i = 0; i < 4; ++i)
    #pragma unroll
    for (int j = 0; j < 4; ++j) acc[i][j] = z4;

  // staging: thread tid -> row = R*64 + (tid>>3), LDS chunk pos = tid&7,
  // global chunk = (tid&7) ^ (row&7)  (row&7 == (tid>>3)&7, R-invariant).
  const int srow = tid >> 3;
  const int scg  = (tid & 7) ^ (srow & 7);
  const bf16_t* agB = A  + (size_t)(bm * BM + srow) * KDIM + scg * 8;
  const bf16_t* bgB = Bm + (size_t)(bn * BN + srow) * KDIM + scg * 8;

  const int fr = lane & 15;   // frag row within 16
  const int fq = lane >> 4;   // quad

  // stage half of tile t (part 0: A rows 0..127 + B rows 0..63;
  //                       part 1: A rows 128..255 + B rows 64..127)
  auto stage = [&](int t, int part) {
    char* base = lds + (t % 3) * BUF_B;
    const int kb = t * BK;
    const int Ra = part * 2;
    async_ld16(agB + (size_t)(Ra * 64) * KDIM + kb,
               base + Ra * 8192 + wave * 1024);
    async_ld16(agB + (size_t)((Ra + 1) * 64) * KDIM + kb,
               base + (Ra + 1) * 8192 + wave * 1024);
    async_ld16(bgB + (size_t)(part * 64) * KDIM + kb,
               base + ABUF_B + part * 8192 + wave * 1024);
  };

  // prologue: tiles 0 and 1 in flight (12 loads/thread)
  stage(0, 0); stage(0, 1);
  stage(1, 0); stage(1, 1);

  #pragma unroll 1
  for (int t = 0; t < NKT - 1; ++t) {
    // tile t ready: own 6 newest (tile t+1) may stay in flight
    asm volatile("s_waitcnt vmcnt(6)" ::: "memory");
    asm volatile("s_barrier" ::: "memory");
    const char* base = lds + (t % 3) * BUF_B;

    Frags f0 = ld_frags(base, 0, waveM, waveN, fr, fq);
    if (t < NKT - 2) stage(t + 2, 0);
    asm volatile("s_barrier" ::: "memory");
    mfma16(f0, acc);

    Frags f1 = ld_frags(base, 1, waveM, waveN, fr, fq);
    if (t < NKT - 2) stage(t + 2, 1);
    asm volatile("s_barrier" ::: "memory");
    mfma16(f1, acc);
  }
  // peeled last tile: drain to 0 (only place vmcnt(0) appears)
  {
    asm volatile("s_waitcnt vmcnt(0)" ::: "memory");
    asm volatile("s_barrier" ::: "memory");
    const char* base = lds + ((NKT - 1) % 3) * BUF_B;
    Frags f0 = ld_frags(base, 0, waveM, waveN, fr, fq);
    mfma16(f0, acc);
    Frags f1 = ld_frags(base, 1, waveM, waveN, fr, fq);
    mfma16(f1, acc);
  }

  // stage this block's 256 labels + label scores into reused LDS
  __syncthreads();
  int*   labL   = (int*)lds;
  float* scoreL = (float*)(lds + 1024);
  if (tid < 256) {
    labL[tid]   = label[bm * BM + tid];
    scoreL[tid] = score32[bm * BM + tid];
  }
  __syncthreads();

  // epilogue: C/D layout col=lane&15, row=(lane>>4)*4+reg [m89-verified]
  const int colBase = bn * BN + waveN * 64 + fr;
  #pragma unroll
  for (int mi = 0; mi < 4; ++mi) {
    #pragma unroll
    for (int r = 0; r < 4; ++r) {
      int rloc = waveM * 64 + mi * 16 + fq * 4 + r;
      int row  = bm * BM + rloc;
      int lab  = labL[rloc];
      float sc = scoreL[rloc];
      float mx = -2.0f;
      #pragma unroll
      for (int ni = 0; ni < 4; ++ni) {
        int col = colBase + ni * 16;
        float v = fminf(fmaxf(acc[mi][ni][r], -1.0f), 1.0f);
        mx = fmaxf(mx, v);                       // flag uses cos incl. label
        float vs = (col == lab) ? sc : SCALE * v;
        if (col < CLASSNUM) out[(size_t)row * CLASSNUM + col] = vs;
      }
      if (mx > FLAG_THR) atomicOr(flags + row, 1u);
    }
  }
}

// ---------------- fixup: early-out unless flagged (rare/never) ------------
// Cold path: exact reference semantics; original label cos reconstructed
// from cls[] since the epilogue already scattered the label score.
__global__ __launch_bounds__(256) void fixup_kernel(
    float* __restrict__ out, const int* __restrict__ label,
    const float* __restrict__ cls, const unsigned* __restrict__ flags) {
  const int row  = blockIdx.x * 4 + (threadIdx.x >> 6);
  const int lane = threadIdx.x & 63;
  if (flags[row] == 0u) return;   // rival scatter value-invisible; label done

  float* orow = out + (size_t)row * CLASSNUM;
  const int lab = label[row];
  const float labv = SCALE * cls[row];   // original 32*cos at label position

  // pass 1: argmax (first-occurrence ties)
  float bv = -1e30f; int bi = 0;
  for (int i = lane; i < CLASSNUM; i += 64) {
    float v = (i == lab) ? labv : orow[i];
    if (v > bv) { bv = v; bi = i; }
  }
  #pragma unroll
  for (int off = 32; off > 0; off >>= 1) {
    float ov = __shfl_xor(bv, off, 64);
    int   oi = __shfl_xor(bi, off, 64);
    if (ov > bv || (ov == bv && oi < bi)) { bv = ov; bi = oi; }
  }
  const float cmax = bv * (1.0f / 32.0f);
  const int maxIdx = bi;

  // pass 2: Z
  float zz = 0.f;
  for (int i = lane; i < CLASSNUM; i += 64) {
    float v = (i == lab) ? labv : orow[i];
    zz += expf(v * (1.0f / 32.0f) - cmax);
  }
  #pragma unroll
  for (int off = 32; off > 0; off >>= 1) zz += __shfl_xor(zz, off, 64);
  const float Z = zz;
  const float thr = 1.0f / Z - EPS2;

  // pass 3: masked argmax (all-masked -> 0)
  float mbv = -1.0f; int mbi = 0;
  for (int i = lane; i < CLASSNUM; i += 64) {
    float v = (i == lab) ? labv : orow[i];
    float soft = expf(v * (1.0f / 32.0f) - cmax) / Z;
    float m = (soft < thr) ? soft : 0.0f;
    if (m > mbv) { mbv = m; mbi = i; }
  }
  #pragma unroll
  for (int off = 32; off > 0; off >>= 1) {
    float ov = __shfl_xor(mbv, off, 64);
    int   oi = __shfl_xor(mbi, off, 64);
    if (ov > mbv || (ov == mbv && oi < mbi)) { mbv = ov; mbi = oi; }
  }

  if (lane == 0) {
    int rival = (maxIdx == lab) ? mbi : maxIdx;
    float rc  = ((rival == lab) ? labv : orow[rival]) * (1.0f / 32.0f);
    float rs  = (rc > 0.6f) ? (rc + MARGIN) * 0.2f : rc;
    orow[rival] = SCALE * rs;                 // rival first
    float cl = cls[row];
    float scv = (cl > 0.0f) ? (cl - MARGIN) : cl;
    orow[lab] = SCALE * scv;                  // label wins collisions
  }
}

extern "C" void kernel_launch(void* const* d_in, const int* in_sizes, int n_in,
                              void* d_out, int out_size, void* d_ws, size_t ws_size,
                              hipStream_t stream) {
  const float* x     = (const float*)d_in[0];
  const int*   label = (const int*)d_in[1];
  const float* w     = (const float*)d_in[2];
  float* out = (float*)d_out;

  // ws: xn bf16 | wn bf16 (padded) | cls f32 | score32 f32 | flags u32
  unsigned short* xn = (unsigned short*)d_ws;
  unsigned short* wn = xn + (size_t)BATCH * KDIM;
  float* cls     = (float*)(wn + (size_t)NPAD * KDIM);
  float* score32 = cls + BATCH;
  unsigned* flags = (unsigned*)(score32 + BATCH);

  // fused prep: x-normalize (1024) | w-normalize (2688) | label-cos (1024)
  prep_fused<<<BATCH / 4 + NPAD / 4 + BATCH / 4, 256, 0, stream>>>(
      x, w, label, xn, wn, cls, score32, flags);

  dim3 g(BATCH / BM, NPAD / BN);   // 16 x 84
  gemm_bf16<<<g, 512, 0, stream>>>((const bf16_t*)xn, (const bf16_t*)wn,
                                   out, flags, label, score32);

  fixup_kernel<<<BATCH / 4, 256, 0, stream>>>(out, label, cls, flags);
}